// Round 6
// baseline (323.153 us; speedup 1.0000x reference)
//
#include <hip/hip_runtime.h>
#include <math.h>

#define KNN    10
#define NPTS   8192
#define HID    64
#define NF     76
#define CHUNKS 16
#define CLEN   (NPTS / CHUNKS)   // 512
#define CAP    24                // pass-2 collection capacity per query
#define F32_INF __uint_as_float(0x7F800000u)

typedef _Float16 h2 __attribute__((ext_vector_type(2)));

// ---------------------------------------------------------------------------
// Prep: pts4[i] = (x, y, z, x^2+y^2+z^2).
// ---------------------------------------------------------------------------
__global__ __launch_bounds__(256) void prep_kernel(const float* __restrict__ cloud,
                                                   float4* __restrict__ pts4) {
    const int i = blockIdx.x * 256 + threadIdx.x;      // 0..32767
    const float x = cloud[i * 3 + 0];
    const float y = cloud[i * 3 + 1];
    const float z = cloud[i * 3 + 2];
    pts4[i] = make_float4(x, y, z, fmaf(z, z, fmaf(y, y, x * x)));
}

// ---------------------------------------------------------------------------
// KNN. Pass 1 finds an UPPER BOUND tau' >= tau (10th-smallest d2) using a
// packed-f16 bubble: d2 rounded UP ((max(d2,0)+1e-7)*(1+2^-10), then RN
// convert -- bump 2^-10 > f16 RN error 2^-11 => converted >= exact), two
// interleaved top-10 lists per (query,chunk) in 10 f16x2 regs,
// v_pk_min/max_f16 via __builtin_elementwise_min/max (2 candidates per op).
// 10th order stat of rounded-up values >= true tau, so pass 2 (exact f32
// compare vs tau') misses nothing; expected extras ~0.02/query (cap 24).
// Phase 3 sorts collected (d2,idx) keys exactly => jax stable top_k.
// Block = 1024 thr = 64 queries x 16 chunks; candidate loads wave-uniform
// (readfirstlane -> s_load).
// ---------------------------------------------------------------------------
__global__ __launch_bounds__(1024) void knn_kernel(const float4* __restrict__ pts4,
                                                   unsigned short* __restrict__ knn_idx) {
    __shared__ unsigned int pk[CHUNKS][64][KNN];   // packed f16x2 lists, 40 KB
    __shared__ unsigned long long coll[64][CAP];   // 12 KB
    __shared__ float tau[64];
    __shared__ int   cnt[64];

    const int t  = threadIdx.x;
    const int c  = t >> 6;                    // chunk 0..15 (wave id)
    const int ql = t & 63;                    // query slot
    const int bx = blockIdx.x;                // 0..511
    const int b  = bx >> 7;                   // batch
    const int n0 = (bx & 127) * 64;
    const int n  = n0 + ql;                   // batch-local query index

    const float4* pb = pts4 + b * NPTS;
    const float4 q = pb[n];
    const float qx = q.x, qy = q.y, qz = q.z, qs = q.w;

    const int cb0 = __builtin_amdgcn_readfirstlane(c * CLEN);
    const float upscale = 1.0009765625f;      // 1 + 2^-10

    // ---------------- pass 1: packed-f16 top-10 upper-bound lists ----------
    h2 bdp[KNN];
    const _Float16 hbig = (_Float16)65504.0f;     // f16 max (finite sentinel)
    const h2 hinf = (h2){hbig, hbig};
#pragma unroll
    for (int s = 0; s < KNN; ++s) bdp[s] = hinf;

#pragma unroll 4
    for (int i = 0; i < CLEN; i += 2) {
        const float4 p0 = pb[cb0 + i];        // uniform -> s_load
        const float4 p1 = pb[cb0 + i + 1];
        const float dot0 = fmaf(p0.z, qz, fmaf(p0.y, qy, p0.x * qx));
        const float dot1 = fmaf(p1.z, qz, fmaf(p1.y, qy, p1.x * qx));
        float d20 = fmaf(-2.0f, dot0, qs + p0.w);
        float d21 = fmaf(-2.0f, dot1, qs + p1.w);
        d20 = (cb0 + i     == n) ? F32_INF : d20;
        d21 = (cb0 + i + 1 == n) ? F32_INF : d21;
        // round UP into f16 domain (clamp to finite sentinel)
        const float u0 = fminf((fmaxf(d20, 0.0f) + 1e-7f) * upscale, 65504.0f);
        const float u1 = fminf((fmaxf(d21, 0.0f) + 1e-7f) * upscale, 65504.0f);
        h2 key = (h2){(_Float16)u0, (_Float16)u1};
#pragma unroll
        for (int s = 0; s < KNN; ++s) {
            const h2 lo = __builtin_elementwise_min(bdp[s], key);
            key = __builtin_elementwise_max(bdp[s], key);
            bdp[s] = lo;
        }
    }

#pragma unroll
    for (int s = 0; s < KNN; ++s) {
        h2 v = bdp[s];
        unsigned int uv;
        __builtin_memcpy(&uv, &v, 4);
        pk[c][ql][s] = uv;
    }
    if (t < 64) cnt[t] = 0;
    __syncthreads();

    // wave 0: merge 16 packed chunk lists (both halves in parallel), then
    // merge the two halves in f32 -> tau' = 10th of all rounded values.
    if (t < 64) {
        h2 md[KNN];
#pragma unroll
        for (int s = 0; s < KNN; ++s) md[s] = hinf;
        for (int cc = 0; cc < CHUNKS; ++cc) {
#pragma unroll
            for (int s = 0; s < KNN; ++s) {
                unsigned int u = pk[cc][t][s];
                h2 key;
                __builtin_memcpy(&key, &u, 4);
#pragma unroll
                for (int uu = 0; uu < KNN; ++uu) {
                    const h2 lo = __builtin_elementwise_min(md[uu], key);
                    key = __builtin_elementwise_max(md[uu], key);
                    md[uu] = lo;
                }
            }
        }
        float lo[KNN];
#pragma unroll
        for (int s = 0; s < KNN; ++s) lo[s] = (float)md[s].x;
#pragma unroll
        for (int s = 0; s < KNN; ++s) {
            float d = (float)md[s].y;
#pragma unroll
            for (int uu = 0; uu < KNN; ++uu) {
                const float l = fminf(lo[uu], d);
                d = fmaxf(lo[uu], d);
                lo[uu] = l;
            }
        }
        tau[t] = lo[KNN - 1];
    }
    __syncthreads();

    // ---------------- pass 2: exact collect (rare hits) ----------------
    const float tq = tau[ql];
#pragma unroll 4
    for (int i = 0; i < CLEN; ++i) {
        const float4 p = pb[cb0 + i];
        const float dot = fmaf(p.z, qz, fmaf(p.y, qy, p.x * qx));
        const float d2 = fmaf(-2.0f, dot, qs + p.w);
        if (d2 <= tq && cb0 + i != n) {
            const unsigned int fb = __float_as_uint(d2);
            const unsigned int m =
                fb ^ ((unsigned int)((int)fb >> 31) | 0x80000000u);  // monotone map
            const unsigned long long key =
                ((unsigned long long)m << 13) | (unsigned long long)(cb0 + i);
            const int slot = atomicAdd(&cnt[ql], 1);
            if (slot < CAP) coll[ql][slot] = key;
        }
    }
    __syncthreads();

    // ---------------- phase 3: exact stable top-10 ----------------
    if (t < 64) {
        const int m = min(cnt[t], CAP);
        unsigned long long md[KNN];
#pragma unroll
        for (int s = 0; s < KNN; ++s) md[s] = ~0ULL;
        for (int cc = 0; cc < CAP; ++cc) {
            unsigned long long key = (cc < m) ? coll[t][cc] : ~0ULL;
#pragma unroll
            for (int u = 0; u < KNN; ++u) {
                const bool lt = key < md[u];
                const unsigned long long lo = lt ? key : md[u];
                key = lt ? md[u] : key;
                md[u] = lo;
            }
        }
        unsigned short* outp = knn_idx + ((size_t)b * NPTS + (n0 + t)) * KNN;
#pragma unroll
        for (int s = 0; s < KNN; ++s)
            outp[s] = (unsigned short)(md[s] & 8191u);
    }
}

// ---------------------------------------------------------------------------
// Features + MLP, 4 threads per point: subh = hidden half (h[32]), subf =
// feature half (38 features). 256-thr blocks, grid 512 -> 2048 waves
// (2/SIMD) and ~half the dependent-FMA chain per thread.
// Feature build + eigen done by one lane per quad (masked lanes cost the
// same issue slots but no duplicate LDS writes / gathers).
// w1s stride 68 so the 4 distinct row addresses per wave spread banks.
// ---------------------------------------------------------------------------
__global__ __launch_bounds__(256) void feat_mlp_kernel(const float4* __restrict__ pts4,
                                                       const float* __restrict__ W1,
                                                       const float* __restrict__ b1,
                                                       const float* __restrict__ W2,
                                                       const float* __restrict__ b2,
                                                       const unsigned short* __restrict__ knn_idx,
                                                       float* __restrict__ out) {
    __shared__ float w1s[NF * 68];            // padded stride
    __shared__ float b1s[HID];
    __shared__ float w2s[HID * 3];
    __shared__ float b2s[3];
    __shared__ float fs[64][NF + 1];          // stride 77

    const int t = threadIdx.x;
    for (int idx = t; idx < NF * HID; idx += 256)
        w1s[(idx >> 6) * 68 + (idx & 63)] = W1[idx];
    if (t < HID) b1s[t] = b1[t];
    if (t < HID * 3) w2s[t] = W2[t];
    if (t < 3) b2s[t] = b2[t];

    const int pl   = t >> 2;                  // point slot 0..63
    const int subh = t & 1;                   // hidden half
    const int subf = (t >> 1) & 1;            // feature half
    const int gid = blockIdx.x * 64 + pl;     // 0..32767
    const int b = gid >> 13;
    const int n = gid & (NPTS - 1);
    const float4* pb = pts4 + b * NPTS;

    if ((t & 3) == 0) {                       // one lane per quad builds
        const float4 cq = pb[n];
        const float cx = cq.x, cy = cq.y, cz = cq.z;

        float nx[KNN], ny[KNN], nz[KNN];
        const unsigned short* ki = knn_idx + (size_t)gid * KNN;
#pragma unroll
        for (int k = 0; k < KNN; ++k) {
            const int j = ki[k];
            const float4 p = pb[j];
            nx[k] = p.x; ny[k] = p.y; nz[k] = p.z;
        }

        float* fr = fs[pl];
        fr[0] = cx; fr[1] = cy; fr[2] = cz;
#pragma unroll
        for (int k = 0; k < KNN; ++k) {
            fr[3 + 3 * k + 0] = nx[k];
            fr[3 + 3 * k + 1] = ny[k];
            fr[3 + 3 * k + 2] = nz[k];
        }
#pragma unroll
        for (int k = 0; k < KNN; ++k) {
            fr[33 + 3 * k + 0] = nx[k] - cx;
            fr[33 + 3 * k + 1] = ny[k] - cy;
            fr[33 + 3 * k + 2] = nz[k] - cz;
        }
#pragma unroll
        for (int k = 0; k < KNN; ++k) {
            const float rx = nx[k] - cx, ry = ny[k] - cy, rz = nz[k] - cz;
            fr[63 + k] = sqrtf(fmaf(rz, rz, fmaf(ry, ry, rx * rx)));
        }

        float mx = 0.f, my = 0.f, mz = 0.f;
#pragma unroll
        for (int k = 0; k < KNN; ++k) { mx += nx[k]; my += ny[k]; mz += nz[k]; }
        mx *= (1.0f / KNN); my *= (1.0f / KNN); mz *= (1.0f / KNN);
        float c00 = 0.f, c01 = 0.f, c02 = 0.f, c11 = 0.f, c12 = 0.f, c22 = 0.f;
#pragma unroll
        for (int k = 0; k < KNN; ++k) {
            const float ex = nx[k] - mx, ey = ny[k] - my, ez = nz[k] - mz;
            c00 = fmaf(ex, ex, c00); c01 = fmaf(ex, ey, c01); c02 = fmaf(ex, ez, c02);
            c11 = fmaf(ey, ey, c11); c12 = fmaf(ey, ez, c12); c22 = fmaf(ez, ez, c22);
        }
        const float sc = 1.0f / (KNN - 1);
        c00 *= sc; c01 *= sc; c02 *= sc; c11 *= sc; c12 *= sc; c22 *= sc;

        const double a00 = c00, a01 = c01, a02 = c02, a11 = c11, a12 = c12, a22 = c22;
        const double qd = (a00 + a11 + a22) / 3.0;
        const double p1 = a01 * a01 + a02 * a02 + a12 * a12;
        const double d00 = a00 - qd, d11 = a11 - qd, d22 = a22 - qd;
        const double p2 = d00 * d00 + d11 * d11 + d22 * d22 + 2.0 * p1;
        double l1, l2, l3;
        if (p2 < 1e-300) {
            l1 = l2 = l3 = qd;
        } else {
            const double p = sqrt(p2 / 6.0);
            const double inv = 1.0 / p;
            const double e00 = d00 * inv, e11 = d11 * inv, e22 = d22 * inv;
            const double e01 = a01 * inv, e02 = a02 * inv, e12 = a12 * inv;
            double detB = e00 * (e11 * e22 - e12 * e12)
                        - e01 * (e01 * e22 - e12 * e02)
                        + e02 * (e01 * e12 - e11 * e02);
            double r = 0.5 * detB;
            r = fmin(1.0, fmax(-1.0, r));
            const double phi = acos(r) / 3.0;
            l1 = qd + 2.0 * p * cos(phi);                          // largest
            l3 = qd + 2.0 * p * cos(phi + 2.0943951023931953);     // smallest
            l2 = 3.0 * qd - l1 - l3;
        }
        fr[73] = (float)((l1 - l2) / l1);
        fr[74] = (float)((l2 - l3) / l1);
        fr[75] = (float)(l3 / l1);
    }

    __syncthreads();   // weights + features visible

    const float* fr = fs[pl];
    const int f0 = subf * 38;

    float h[32];
#pragma unroll
    for (int j = 0; j < 32; ++j) h[j] = (subf == 0) ? b1s[subh * 32 + j] : 0.0f;

#pragma unroll 2
    for (int ff = 0; ff < 38; ++ff) {
        const int f = f0 + ff;
        const float v = fr[f];
        const float4* w4 = reinterpret_cast<const float4*>(w1s + f * 68 + subh * 32);
#pragma unroll
        for (int j4 = 0; j4 < 8; ++j4) {
            const float4 w = w4[j4];
            h[4 * j4 + 0] = fmaf(v, w.x, h[4 * j4 + 0]);
            h[4 * j4 + 1] = fmaf(v, w.y, h[4 * j4 + 1]);
            h[4 * j4 + 2] = fmaf(v, w.z, h[4 * j4 + 2]);
            h[4 * j4 + 3] = fmaf(v, w.w, h[4 * j4 + 3]);
        }
    }

    // combine feature halves (lanes differing in bit 1)
#pragma unroll
    for (int j = 0; j < 32; ++j) h[j] += __shfl_xor(h[j], 2, 64);

    float o0 = 0.f, o1 = 0.f, o2 = 0.f;
#pragma unroll
    for (int j = 0; j < 32; ++j) {
        const float r = fmaxf(h[j], 0.0f);
        const int jj = subh * 32 + j;
        o0 = fmaf(r, w2s[jj * 3 + 0], o0);
        o1 = fmaf(r, w2s[jj * 3 + 1], o1);
        o2 = fmaf(r, w2s[jj * 3 + 2], o2);
    }
    // combine hidden halves (lanes differing in bit 0)
    o0 += __shfl_xor(o0, 1, 64);
    o1 += __shfl_xor(o1, 1, 64);
    o2 += __shfl_xor(o2, 1, 64);

    if ((t & 3) == 0) {
        float* op = out + (size_t)gid * 3;
        op[0] = fmaxf(o0 + b2s[0], 0.0f);
        op[1] = fmaxf(o1 + b2s[1], 0.0f);
        op[2] = fmaxf(o2 + b2s[2], 0.0f);
    }
}

extern "C" void kernel_launch(void* const* d_in, const int* in_sizes, int n_in,
                              void* d_out, int out_size, void* d_ws, size_t ws_size,
                              hipStream_t stream) {
    const float* cloud = (const float*)d_in[0];   // [4,8192,3]
    const float* W1    = (const float*)d_in[1];   // [76,64]
    const float* b1    = (const float*)d_in[2];   // [64]
    const float* W2    = (const float*)d_in[3];   // [64,3]
    const float* b2    = (const float*)d_in[4];   // [3]
    float* out = (float*)d_out;                   // [4,8192,3]

    float4* pts4 = (float4*)d_ws;                                          // 512 KB
    unsigned short* knn = (unsigned short*)((char*)d_ws + 4 * NPTS * 16);  // 640 KB

    prep_kernel<<<dim3(128), dim3(256), 0, stream>>>(cloud, pts4);
    knn_kernel<<<dim3(512), dim3(1024), 0, stream>>>(pts4, knn);
    feat_mlp_kernel<<<dim3(512), dim3(256), 0, stream>>>(pts4, W1, b1, W2, b2, knn, out);
}